// Round 12
// baseline (539.605 us; speedup 1.0000x reference)
//
#include <hip/hip_runtime.h>
#include <hip/hip_bf16.h>

#define Bz 16
#define Tz 256
#define T2z 16
#define Hz 256
#define DRz 64
#define DEPTHz 8
#define ROWSz (Bz * (Tz + 2))   // 4128 rows in flat h/c tables
#define NODESz (Bz * Tz)        // 4096 tree nodes

typedef short bf16x8 __attribute__((ext_vector_type(8)));
typedef float f32x4 __attribute__((ext_vector_type(4)));

__device__ __forceinline__ float sigmoid_(float x) { return 1.0f / (1.0f + __expf(-x)); }
__device__ __forceinline__ float tanh_(float x) {
    float e = __expf(2.0f * x);
    return 1.0f - 2.0f / (e + 1.0f);
}
__device__ __forceinline__ short f2b(float f) {
    __hip_bfloat16 h = __float2bfloat16(f);
    return *(short*)&h;
}
__device__ __forceinline__ float b2f(short s) {
    return __uint_as_float(((unsigned)(unsigned short)s) << 16);
}
__device__ __forceinline__ void gload16(const short* g, short* l) {
    __builtin_amdgcn_global_load_lds((const __attribute__((address_space(1))) void*)g,
                                     (__attribute__((address_space(3))) void*)l, 16, 0, 0);
}

// C[M,N] = A[M,K]_bf16 @ BT[N,K]^T (+bias). Output fp32 (C) or bf16 (Cb).
__global__ __launch_bounds__(256) void bgemm_k(const short* __restrict__ A,
                                               const short* __restrict__ BT,
                                               const float* __restrict__ bias,
                                               float* __restrict__ C,
                                               short* __restrict__ Cb,
                                               int K, int N) {
    __shared__ short As[64 * 32];
    __shared__ short Bs[64 * 32];
    const int tid = threadIdx.x;
    const int w = tid >> 6, lane = tid & 63;
    const int m0 = blockIdx.y * 64, n0 = blockIdx.x * 64;
    const int r16 = lane & 15, q = lane >> 4;
    f32x4 acc[4] = {};
    const short* ga = A + (size_t)(m0 + w * 16 + (lane >> 2)) * K + (lane & 3) * 8;
    const short* gb = BT + (size_t)(n0 + w * 16 + (lane >> 2)) * K + (lane & 3) * 8;
    short* la = As + w * 512;
    short* lb = Bs + w * 512;
    for (int kt = 0; kt < K; kt += 32) {
        __syncthreads();
        gload16(ga + kt, la);
        gload16(gb + kt, lb);
        __syncthreads();
        bf16x8 bfrag = *(const bf16x8*)&Bs[(w * 16 + r16) * 32 + q * 8];
#pragma unroll
        for (int i = 0; i < 4; i++) {
            bf16x8 afrag = *(const bf16x8*)&As[(i * 16 + r16) * 32 + q * 8];
            acc[i] = __builtin_amdgcn_mfma_f32_16x16x32_bf16(afrag, bfrag, acc[i], 0, 0, 0);
        }
    }
    const int col = n0 + w * 16 + r16;
    const float bv = bias ? bias[col] : 0.0f;
#pragma unroll
    for (int i = 0; i < 4; i++)
#pragma unroll
        for (int r = 0; r < 4; r++) {
            const size_t o = (size_t)(m0 + i * 16 + q * 4 + r) * N + col;
            if (Cb) Cb[o] = f2b(acc[i][r] + bv);
            else    C[o]  = acc[i][r] + bv;
        }
}

// One-time weight prep: bf16 transposes + composed proj bias [0 | b_hf].
__global__ __launch_bounds__(256) void prep_w_k(const float* __restrict__ Wx,
                                                const float* __restrict__ Whp,
                                                const float* __restrict__ Whf,
                                                const float* __restrict__ bhf,
                                                const float* __restrict__ Whiou,
                                                const float* __restrict__ Wdep,
                                                short* __restrict__ WTx,
                                                short* __restrict__ WTcat,
                                                short* __restrict__ WThiou,
                                                short* __restrict__ WTdep,
                                                float* __restrict__ bias_cat) {
    int e = blockIdx.x * 256 + threadIdx.x;
    if (e < 262144) { int n = e >> 8, k = e & 255; WTx[e] = f2b(Wx[k * 1024 + n]); return; }
    e -= 262144;
    if (e < 131072) {
        int n = e >> 8, k = e & 255;
        WTcat[e] = f2b((n < 256) ? Whp[k * 256 + n] : Whf[k * 256 + (n - 256)]);
        return;
    }
    e -= 131072;
    if (e < 196608) { int n = e >> 8, k = e & 255; WThiou[e] = f2b(Whiou[k * 768 + n]); return; }
    e -= 196608;
    if (e < 16384) { int n = e >> 6, k = e & 63; WTdep[e] = f2b(Wdep[k * 256 + n]); return; }
    e -= 16384;
    if (e < 512) bias_cat[e] = (e < 256) ? 0.0f : bhf[e - 256];
}

// Merged fp32->bf16 casts: tok (262144 float4) then cdep (1048576 float4).
__global__ __launch_bounds__(256) void cast2_k(const float* __restrict__ tok,
                                               const float* __restrict__ cdep,
                                               short* __restrict__ tok_b,
                                               short* __restrict__ cdep_b) {
    const int i = blockIdx.x * 256 + threadIdx.x;
    const float* s; short* d; int k;
    if (i < 262144) { s = tok; d = tok_b; k = i; }
    else { s = cdep; d = cdep_b; k = i - 262144; }
    float4 v = ((const float4*)s)[k];
    short4 o; o.x = f2b(v.x); o.y = f2b(v.y); o.z = f2b(v.z); o.w = f2b(v.w);
    ((short4*)d)[k] = o;
}

// Init BOTH ping-pong tables to level-0 zero-state: [ph=0|pf=b_hf|rh=0|cb=0].
// Pad rows keep this state forever (ref: pad rows are h=c=0).
__global__ __launch_bounds__(256) void init2_k(const float* __restrict__ bhf,
                                               short* __restrict__ tab0,
                                               short* __restrict__ tab1) {
    const int r = blockIdx.x, tid = threadIdx.x;
    const short bh = f2b(bhf[tid]);
    short* r0 = tab0 + (size_t)r * 1024;
    short* r1 = tab1 + (size_t)r * 1024;
    r0[tid] = 0; r0[256 + tid] = bh; r0[512 + tid] = 0; r0[768 + tid] = 0;
    r1[tid] = 0; r1[256 + tid] = bh; r1[512 + tid] = 0; r1[768 + tid] = 0;
}

// Level 0 only: h=c=0 exactly => h_iou=0, fsum=0; gates are elementwise on
// x_iou + b_hiou, then renorm + proj MFMA. Writes packed tab rows.
__global__ __launch_bounds__(512, 2) void post0_k(const short* __restrict__ xiou_b,
                                                  const float* __restrict__ b_hiou,
                                                  const short* __restrict__ WTcat,
                                                  const float* __restrict__ biascat,
                                                  short* __restrict__ tab) {
    __shared__ short htA[16 * 264];
    const int tid = threadIdx.x;
    const int w = tid >> 6, lane = tid & 63;
    const int r16 = lane & 15, q = lane >> 4;
    const int node0 = blockIdx.x * 16;
    const int b = node0 >> 8, t0 = node0 & 255;

    // gates: thread t: node nl = t>>5, elems e0g..e0g+7
    {
        const int nl = tid >> 5, e0g = (tid & 31) * 8;
        const int gnode = node0 + nl;
        const short* xr = xiou_b + (size_t)gnode * 1024;
        float hn[8], cn[8], hs = 0.0f, cs = 0.0f;
#pragma unroll
        for (int u = 0; u < 8; u += 4) {
            short4 xi = *(const short4*)(xr + e0g + u);
            short4 xo = *(const short4*)(xr + 256 + e0g + u);
            short4 xu = *(const short4*)(xr + 512 + e0g + u);
            float4 bi = *(const float4*)(b_hiou + e0g + u);
            float4 bo = *(const float4*)(b_hiou + 256 + e0g + u);
            float4 bu = *(const float4*)(b_hiou + 512 + e0g + u);
            float iv[4] = { b2f(xi.x) + bi.x, b2f(xi.y) + bi.y, b2f(xi.z) + bi.z, b2f(xi.w) + bi.w };
            float ov[4] = { b2f(xo.x) + bo.x, b2f(xo.y) + bo.y, b2f(xo.z) + bo.z, b2f(xo.w) + bo.w };
            float uv[4] = { b2f(xu.x) + bu.x, b2f(xu.y) + bu.y, b2f(xu.z) + bu.z, b2f(xu.w) + bu.w };
#pragma unroll
            for (int z = 0; z < 4; z++) {
                const float c = sigmoid_(iv[z]) * tanh_(uv[z]);
                const float h = sigmoid_(ov[z]) * tanh_(c);
                cn[u + z] = c; hn[u + z] = h;
                hs = fmaf(h, h, hs); cs = fmaf(c, c, cs);
            }
        }
#pragma unroll
        for (int off = 16; off > 0; off >>= 1) {
            hs += __shfl_xor(hs, off);
            cs += __shfl_xor(cs, off);
        }
        const float nh = sqrtf(hs), ncv = sqrtf(cs);
        const float sh = nh > 2.0f ? 2.0f / nh : 1.0f;
        const float sc = ncv > 2.0f ? 2.0f / ncv : 1.0f;
        const size_t grow = (size_t)b * (Tz + 2) + t0 + nl + 2;
        short hb[8], cb[8];
#pragma unroll
        for (int u = 0; u < 8; u++) { hb[u] = f2b(hn[u] * sh); cb[u] = f2b(cn[u] * sc); }
#pragma unroll
        for (int u = 0; u < 8; u += 4) {
            *(short4*)(tab + grow * 1024 + 512 + e0g + u) = *(short4*)&hb[u];
            *(short4*)(tab + grow * 1024 + 768 + e0g + u) = *(short4*)&cb[u];
            *(short4*)(htA + nl * 264 + e0g + u) = *(short4*)&hb[u];
        }
    }
    __syncthreads();
    // proj: [ph|pf] = rn_h(16x256) @ [W_hproj|W_hf] + [0|b_hf] -> tab 0..511
    for (int f = 0; f < 4; f++) {
        const int nf = w * 4 + f;
        f32x4 acc = {};
#pragma unroll
        for (int kt = 0; kt < 8; kt++) {
            bf16x8 af = *(const bf16x8*)(htA + r16 * 264 + kt * 32 + q * 8);
            bf16x8 bf = *(const bf16x8*)(WTcat + (size_t)(nf * 16 + r16) * 256 + kt * 32 + q * 8);
            acc = __builtin_amdgcn_mfma_f32_16x16x32_bf16(af, bf, acc, 0, 0, 0);
        }
        const int col = nf * 16 + r16;
        const float bc = biascat[col];
#pragma unroll
        for (int r = 0; r < 4; r++) {
            const size_t grow = (size_t)b * (Tz + 2) + t0 + q * 4 + r + 2;
            tab[grow * 1024 + col] = f2b(acc[r] + bc);
        }
    }
}

// Levels 1..7: ONE dispatch per level. 512 blocks x 512 threads (8 waves).
// Block owns 8 nodes end-to-end: attn (wave<->node, 16 children in 4
// prefetched quads, exact-max softmax) -> h_iou MFMA -> gates (fs in regs)
// -> renorm -> proj MFMA. Reads tabI, writes tabO (ping-pong; the dispatch
// boundary is the only global sync needed).
__global__ __launch_bounds__(512, 4) void level_k(const int* __restrict__ trees,
                                                  const float* __restrict__ cmask,
                                                  const short* __restrict__ tabI,
                                                  const short* __restrict__ dp_b,
                                                  const float* __restrict__ attnv,
                                                  const short* __restrict__ xiou_b,
                                                  const short* __restrict__ WThiou,
                                                  const float* __restrict__ b_hiou,
                                                  const short* __restrict__ WTcat,
                                                  const float* __restrict__ biascat,
                                                  short* __restrict__ tabO,
                                                  float* __restrict__ out,
                                                  int last) {
    __shared__ int   sidx[128];
    __shared__ float smask[128];
    __shared__ short xfL[16 * 256];    // 8 KB
    __shared__ short tileA[16 * 264];  // 8.25 KB: hj tile, then renormed-h tile
    __shared__ float hiouL[8 * 768];   // 24 KB
    __shared__ float bhL[768];         // 3 KB

    const int tid = threadIdx.x;
    const int w = tid >> 6, lane = tid & 63;
    const int e0 = lane * 4;
    const int r16 = lane & 15, q = lane >> 4;
    const int node0 = blockIdx.x * 8;
    const int b = node0 >> 8, t0 = node0 & 255;
    const int node = node0 + w;
    const int cb0 = w * 16;

    // ---- prologue ----
    if (tid < 128) {
        sidx[tid] = trees[node0 * 16 + tid];
        smask[tid] = cmask[node0 * 16 + tid];
    }
    {   // x_f rows j=0..15 of batch b (bf16, cols 768..1023): 512 int4s
        const int j = tid >> 5, cc = (tid & 31) * 8;
        *(int4*)(xfL + j * 256 + cc) =
            *(const int4*)(xiou_b + (size_t)(b * 256 + j) * 1024 + 768 + cc);
    }
    if (tid < 192) ((float4*)bhL)[tid] = ((const float4*)b_hiou)[tid];
    if (tid < 264) ((int4*)(tileA + 8 * 264))[tid] = make_int4(0, 0, 0, 0);  // pad rows
    const float4 av = *(const float4*)(attnv + e0);
    __syncthreads();

    // ---- attn: wave w -> node; 16 children in 4 prefetched quads ----
    float lg[16];
#pragma unroll
    for (int j = 0; j < 16; j++) lg[j] = -1e30f;
#pragma unroll
    for (int g = 0; g < 4; g++) {
        short4 ph4[4], dv4[4];
        bool act[4];
#pragma unroll
        for (int c = 0; c < 4; c++) {
            const int j = g * 4 + c;
            act[c] = (smask[cb0 + j] != 0.0f);
            if (act[c]) {
                ph4[c] = *(const short4*)(tabI + (size_t)sidx[cb0 + j] * 1024 + e0);
                dv4[c] = *(const short4*)(dp_b + ((size_t)node * 16 + j) * 256 + e0);
            }
        }
#pragma unroll
        for (int c = 0; c < 4; c++) {
            if (!act[c]) continue;
            float s = tanh_(b2f(ph4[c].x) + b2f(dv4[c].x)) * av.x
                    + tanh_(b2f(ph4[c].y) + b2f(dv4[c].y)) * av.y
                    + tanh_(b2f(ph4[c].z) + b2f(dv4[c].z)) * av.z
                    + tanh_(b2f(ph4[c].w) + b2f(dv4[c].w)) * av.w;
#pragma unroll
            for (int off = 32; off > 0; off >>= 1) s += __shfl_xor(s, off);
            lg[g * 4 + c] = s;  // butterfly leaves sum in ALL lanes
        }
    }
    float mx = -1e30f;
#pragma unroll
    for (int j = 0; j < 16; j++) mx = fmaxf(mx, lg[j]);
    float den = 0.0f;
#pragma unroll
    for (int j = 0; j < 16; j++) den += __expf(lg[j] - mx);
    const float inv = 1.0f / den;  // all-masked: weights unused (all j skipped)

    float hj[4] = {}, fs[4] = {};
#pragma unroll
    for (int g = 0; g < 4; g++) {
        short4 pf4[4], rh4[4], cb4[4], xf4[4];
        bool act[4];
#pragma unroll
        for (int c = 0; c < 4; c++) {
            const int j = g * 4 + c;
            act[c] = (smask[cb0 + j] != 0.0f);
            if (act[c]) {
                const short* row = tabI + (size_t)sidx[cb0 + j] * 1024;
                pf4[c] = *(const short4*)(row + 256 + e0);
                rh4[c] = *(const short4*)(row + 512 + e0);
                cb4[c] = *(const short4*)(row + 768 + e0);
                xf4[c] = *(const short4*)(xfL + j * 256 + e0);
            }
        }
#pragma unroll
        for (int c = 0; c < 4; c++) {
            if (!act[c]) continue;  // exact: ref multiplies masked terms by 0
            const float wt = __expf(lg[g * 4 + c] - mx) * inv;
            hj[0] = fmaf(b2f(rh4[c].x), wt, hj[0]);
            hj[1] = fmaf(b2f(rh4[c].y), wt, hj[1]);
            hj[2] = fmaf(b2f(rh4[c].z), wt, hj[2]);
            hj[3] = fmaf(b2f(rh4[c].w), wt, hj[3]);
            fs[0] = fmaf(sigmoid_(b2f(xf4[c].x) + b2f(pf4[c].x)), b2f(cb4[c].x), fs[0]);
            fs[1] = fmaf(sigmoid_(b2f(xf4[c].y) + b2f(pf4[c].y)), b2f(cb4[c].y), fs[1]);
            fs[2] = fmaf(sigmoid_(b2f(xf4[c].z) + b2f(pf4[c].z)), b2f(cb4[c].z), fs[2]);
            fs[3] = fmaf(sigmoid_(b2f(xf4[c].w) + b2f(pf4[c].w)), b2f(cb4[c].w), fs[3]);
        }
    }
    {
        short4 o; o.x = f2b(hj[0]); o.y = f2b(hj[1]); o.z = f2b(hj[2]); o.w = f2b(hj[3]);
        *(short4*)(tileA + w * 264 + e0) = o;
    }
    __syncthreads();

    // ---- h_iou = hj(8x256) @ W_hiou: 6 N-frags per wave (48 total) ----
#pragma unroll
    for (int f = 0; f < 6; f++) {
        const int nf = w * 6 + f;
        f32x4 acc = {};
#pragma unroll
        for (int kt = 0; kt < 8; kt++) {
            bf16x8 af = *(const bf16x8*)(tileA + r16 * 264 + kt * 32 + q * 8);
            bf16x8 bf = *(const bf16x8*)(WThiou + (size_t)(nf * 16 + r16) * 256 + kt * 32 + q * 8);
            acc = __builtin_amdgcn_mfma_f32_16x16x32_bf16(af, bf, acc, 0, 0, 0);
        }
#pragma unroll
        for (int r = 0; r < 4; r++) {
            const int m = q * 4 + r;
            if (m < 8) hiouL[m * 768 + nf * 16 + r16] = acc[r];
        }
    }
    __syncthreads();

    // ---- gates: wave w -> node; fs still in regs ----
    {
        const short* xr = xiou_b + (size_t)node * 1024;
        short4 xi = *(const short4*)(xr + e0);
        short4 xo = *(const short4*)(xr + 256 + e0);
        short4 xu = *(const short4*)(xr + 512 + e0);
        float4 bi = *(const float4*)(bhL + e0);
        float4 bo = *(const float4*)(bhL + 256 + e0);
        float4 bu = *(const float4*)(bhL + 512 + e0);
        float4 hi = *(const float4*)(hiouL + w * 768 + e0);
        float4 ho = *(const float4*)(hiouL + w * 768 + 256 + e0);
        float4 hu = *(const float4*)(hiouL + w * 768 + 512 + e0);
        float iv[4] = { b2f(xi.x) + hi.x + bi.x, b2f(xi.y) + hi.y + bi.y,
                        b2f(xi.z) + hi.z + bi.z, b2f(xi.w) + hi.w + bi.w };
        float ov[4] = { b2f(xo.x) + ho.x + bo.x, b2f(xo.y) + ho.y + bo.y,
                        b2f(xo.z) + ho.z + bo.z, b2f(xo.w) + ho.w + bo.w };
        float uv[4] = { b2f(xu.x) + hu.x + bu.x, b2f(xu.y) + hu.y + bu.y,
                        b2f(xu.z) + hu.z + bu.z, b2f(xu.w) + hu.w + bu.w };
        float hn[4], cn[4], hs = 0.0f, cs = 0.0f;
#pragma unroll
        for (int z = 0; z < 4; z++) {
            const float c = fmaf(sigmoid_(iv[z]), tanh_(uv[z]), fs[z]);
            const float h = sigmoid_(ov[z]) * tanh_(c);
            cn[z] = c; hn[z] = h;
            hs = fmaf(h, h, hs); cs = fmaf(c, c, cs);
        }
        if (last) {
            *(float4*)(out + (size_t)node * 256 + e0) =
                make_float4(hn[0], hn[1], hn[2], hn[3]);
        } else {
#pragma unroll
            for (int off = 32; off > 0; off >>= 1) {
                hs += __shfl_xor(hs, off);
                cs += __shfl_xor(cs, off);
            }
            const float nh = sqrtf(hs), ncv = sqrtf(cs);
            const float sh = nh > 2.0f ? 2.0f / nh : 1.0f;
            const float sc = ncv > 2.0f ? 2.0f / ncv : 1.0f;
            const size_t grow = (size_t)b * (Tz + 2) + t0 + w + 2;
            short4 hb4, cbv;
            hb4.x = f2b(hn[0] * sh); hb4.y = f2b(hn[1] * sh);
            hb4.z = f2b(hn[2] * sh); hb4.w = f2b(hn[3] * sh);
            cbv.x = f2b(cn[0] * sc); cbv.y = f2b(cn[1] * sc);
            cbv.z = f2b(cn[2] * sc); cbv.w = f2b(cn[3] * sc);
            *(short4*)(tabO + grow * 1024 + 512 + e0) = hb4;
            *(short4*)(tabO + grow * 1024 + 768 + e0) = cbv;
            *(short4*)(tileA + w * 264 + e0) = hb4;
        }
    }
    if (!last) {
        __syncthreads();  // renormed-h tile ready
        // ---- proj: [ph|pf] = rn_h(8x256) @ [W_hproj|W_hf] + [0|b_hf] ----
#pragma unroll
        for (int f = 0; f < 4; f++) {
            const int nf = w * 4 + f;
            f32x4 acc = {};
#pragma unroll
            for (int kt = 0; kt < 8; kt++) {
                bf16x8 af = *(const bf16x8*)(tileA + r16 * 264 + kt * 32 + q * 8);
                bf16x8 bf = *(const bf16x8*)(WTcat + (size_t)(nf * 16 + r16) * 256 + kt * 32 + q * 8);
                acc = __builtin_amdgcn_mfma_f32_16x16x32_bf16(af, bf, acc, 0, 0, 0);
            }
            const int col = nf * 16 + r16;
            const float bc = biascat[col];
#pragma unroll
            for (int r = 0; r < 4; r++) {
                const int m = q * 4 + r;
                if (m < 8) {
                    const size_t grow = (size_t)b * (Tz + 2) + t0 + m + 2;
                    tabO[grow * 1024 + col] = f2b(acc[r] + bc);
                }
            }
        }
    }
}

extern "C" void kernel_launch(void* const* d_in, const int* in_sizes, int n_in,
                              void* d_out, int out_size, void* d_ws, size_t ws_size,
                              hipStream_t stream) {
    const float* tok     = (const float*)d_in[0];
    const int*   trees   = (const int*)d_in[1];
    const float* cmask   = (const float*)d_in[2];
    const float* cdep    = (const float*)d_in[4];
    const float* W_xiouf = (const float*)d_in[5];
    const float* b_xiouf = (const float*)d_in[6];
    const float* W_hiou  = (const float*)d_in[7];
    const float* b_hiou  = (const float*)d_in[8];
    const float* W_hf    = (const float*)d_in[9];
    const float* b_hf    = (const float*)d_in[10];
    const float* W_dep   = (const float*)d_in[11];
    const float* W_hp    = (const float*)d_in[12];
    const float* W_attnv = (const float*)d_in[13];
    float* out = (float*)d_out;

    char* p = (char*)d_ws;
    auto alloc = [&](size_t bytes) { char* q = p; p += (bytes + 255) & ~255ull; return q; };
    short* tab0   = (short*)alloc((size_t)ROWSz * 1024 * 2);       // 8.5 MB packed
    short* tab1   = (short*)alloc((size_t)ROWSz * 1024 * 2);       // 8.5 MB packed
    short* dp_b   = (short*)alloc((size_t)NODESz * 16 * 256 * 2);  // 33.5 MB
    short* xiou_b = (short*)alloc((size_t)NODESz * 1024 * 2);      // 8.4 MB bf16
    short* tok_b  = (short*)alloc((size_t)NODESz * 256 * 2);
    short* cdep_b = (short*)alloc((size_t)NODESz * 16 * 64 * 2);
    short* WTx    = (short*)alloc(262144 * 2);
    short* WTcat  = (short*)alloc(131072 * 2);
    short* WThiou = (short*)alloc(196608 * 2);
    short* WTdep  = (short*)alloc(16384 * 2);
    float* biascat= (float*)alloc(512 * 4);

    prep_w_k<<<2370, 256, 0, stream>>>(W_xiouf, W_hp, W_hf, b_hf, W_hiou, W_dep,
                                       WTx, WTcat, WThiou, WTdep, biascat);
    cast2_k<<<5120, 256, 0, stream>>>(tok, cdep, tok_b, cdep_b);
    init2_k<<<ROWSz, 256, 0, stream>>>(b_hf, tab0, tab1);

    // Loop-invariant GEMMs: x_iou (bf16 out incl. bias) and deprel projection
    bgemm_k<<<dim3(16, 64), 256, 0, stream>>>(tok_b, WTx, b_xiouf, nullptr, xiou_b, 256, 1024);
    bgemm_k<<<dim3(4, 1024), 256, 0, stream>>>(cdep_b, WTdep, nullptr, nullptr, dp_b, 64, 256);

    // Level 0: h=c=0 => no gathers; elementwise gates + proj only -> tab0.
    post0_k<<<NODESz / 16, 512, 0, stream>>>(xiou_b, b_hiou, WTcat, biascat, tab0);

    // Levels 1..7: one fused dispatch per level, ping-pong tables.
    short* tabs[2] = { tab0, tab1 };
    for (int lvl = 1; lvl < DEPTHz; lvl++) {
        level_k<<<NODESz / 8, 512, 0, stream>>>(trees, cmask, tabs[(lvl + 1) & 1],
                                                dp_b, W_attnv, xiou_b,
                                                WThiou, b_hiou, WTcat, biascat,
                                                tabs[lvl & 1], out, lvl == DEPTHz - 1);
    }
}

// Round 13
// 485.040 us; speedup vs baseline: 1.1125x; 1.1125x over previous
//
#include <hip/hip_runtime.h>
#include <hip/hip_bf16.h>

#define Bz 16
#define Tz 256
#define T2z 16
#define Hz 256
#define DRz 64
#define DEPTHz 8
#define ROWSz (Bz * (Tz + 2))   // 4128 rows in flat h/c tables
#define NODESz (Bz * Tz)        // 4096 tree nodes

typedef short bf16x8 __attribute__((ext_vector_type(8)));
typedef float f32x4 __attribute__((ext_vector_type(4)));

__device__ __forceinline__ float sigmoid_(float x) { return 1.0f / (1.0f + __expf(-x)); }
__device__ __forceinline__ float tanh_(float x) {
    float e = __expf(2.0f * x);
    return 1.0f - 2.0f / (e + 1.0f);
}
__device__ __forceinline__ short f2b(float f) {
    __hip_bfloat16 h = __float2bfloat16(f);
    return *(short*)&h;
}
__device__ __forceinline__ float b2f(short s) {
    return __uint_as_float(((unsigned)(unsigned short)s) << 16);
}
__device__ __forceinline__ void gload16(const short* g, short* l) {
    __builtin_amdgcn_global_load_lds((const __attribute__((address_space(1))) void*)g,
                                     (__attribute__((address_space(3))) void*)l, 16, 0, 0);
}

// C[M,N] = A[M,K]_bf16 @ BT[N,K]^T (+bias). Output fp32 (C) or bf16 (Cb).
__global__ __launch_bounds__(256) void bgemm_k(const short* __restrict__ A,
                                               const short* __restrict__ BT,
                                               const float* __restrict__ bias,
                                               float* __restrict__ C,
                                               short* __restrict__ Cb,
                                               int K, int N) {
    __shared__ short As[64 * 32];
    __shared__ short Bs[64 * 32];
    const int tid = threadIdx.x;
    const int w = tid >> 6, lane = tid & 63;
    const int m0 = blockIdx.y * 64, n0 = blockIdx.x * 64;
    const int r16 = lane & 15, q = lane >> 4;
    f32x4 acc[4] = {};
    const short* ga = A + (size_t)(m0 + w * 16 + (lane >> 2)) * K + (lane & 3) * 8;
    const short* gb = BT + (size_t)(n0 + w * 16 + (lane >> 2)) * K + (lane & 3) * 8;
    short* la = As + w * 512;
    short* lb = Bs + w * 512;
    for (int kt = 0; kt < K; kt += 32) {
        __syncthreads();
        gload16(ga + kt, la);
        gload16(gb + kt, lb);
        __syncthreads();
        bf16x8 bfrag = *(const bf16x8*)&Bs[(w * 16 + r16) * 32 + q * 8];
#pragma unroll
        for (int i = 0; i < 4; i++) {
            bf16x8 afrag = *(const bf16x8*)&As[(i * 16 + r16) * 32 + q * 8];
            acc[i] = __builtin_amdgcn_mfma_f32_16x16x32_bf16(afrag, bfrag, acc[i], 0, 0, 0);
        }
    }
    const int col = n0 + w * 16 + r16;
    const float bv = bias ? bias[col] : 0.0f;
#pragma unroll
    for (int i = 0; i < 4; i++)
#pragma unroll
        for (int r = 0; r < 4; r++) {
            const size_t o = (size_t)(m0 + i * 16 + q * 4 + r) * N + col;
            if (Cb) Cb[o] = f2b(acc[i][r] + bv);
            else    C[o]  = acc[i][r] + bv;
        }
}

// One merged prep kernel: weight transposes + composed bias + input casts +
// level-0 table init (all independent elementwise work; range-dispatched).
__global__ __launch_bounds__(256) void prep_all_k(const float* __restrict__ Wx,
                                                  const float* __restrict__ Whp,
                                                  const float* __restrict__ Whf,
                                                  const float* __restrict__ bhf,
                                                  const float* __restrict__ Whiou,
                                                  const float* __restrict__ Wdep,
                                                  const float* __restrict__ tok,
                                                  const float* __restrict__ cdep,
                                                  short* __restrict__ WTx,
                                                  short* __restrict__ WTcat,
                                                  short* __restrict__ WThiou,
                                                  short* __restrict__ WTdep,
                                                  float* __restrict__ bias_cat,
                                                  short* __restrict__ tok_b,
                                                  short* __restrict__ cdep_b,
                                                  short* __restrict__ tab) {
    long e = (long)blockIdx.x * 256 + threadIdx.x;
    if (e < 262144) { int n = e >> 8, k = e & 255; WTx[e] = f2b(Wx[k * 1024 + n]); return; }
    e -= 262144;
    if (e < 131072) {
        int n = e >> 8, k = e & 255;
        WTcat[e] = f2b((n < 256) ? Whp[k * 256 + n] : Whf[k * 256 + (n - 256)]);
        return;
    }
    e -= 131072;
    if (e < 196608) { int n = e >> 8, k = e & 255; WThiou[e] = f2b(Whiou[k * 768 + n]); return; }
    e -= 196608;
    if (e < 16384) { int n = e >> 6, k = e & 63; WTdep[e] = f2b(Wdep[k * 256 + n]); return; }
    e -= 16384;
    if (e < 512) { bias_cat[e] = (e < 256) ? 0.0f : bhf[e - 256]; return; }
    e -= 512;
    if (e < 262144) {  // tok cast, float4 units
        float4 v = ((const float4*)tok)[e];
        short4 o; o.x = f2b(v.x); o.y = f2b(v.y); o.z = f2b(v.z); o.w = f2b(v.w);
        ((short4*)tok_b)[e] = o;
        return;
    }
    e -= 262144;
    if (e < 1048576) {  // cdep cast, float4 units
        float4 v = ((const float4*)cdep)[e];
        short4 o; o.x = f2b(v.x); o.y = f2b(v.y); o.z = f2b(v.z); o.w = f2b(v.w);
        ((short4*)cdep_b)[e] = o;
        return;
    }
    e -= 1048576;
    if (e < 1056768) {  // level-0 packed table: [ph=0 | pf=b_hf | rh=0 | cb=0]
        const int r = e >> 8, c = e & 255;
        short* row = tab + (size_t)r * 1024;
        row[c] = 0;
        row[256 + c] = f2b(bhf[c]);
        row[512 + c] = 0;
        row[768 + c] = 0;
    }
}
#define PREP_THREADS (262144L + 131072 + 196608 + 16384 + 512 + 262144 + 1048576 + 1056768)
#define PREP_BLOCKS ((int)((PREP_THREADS + 255) / 256))

// Gather stage: 2 nodes/block (2048 blocks x 512 threads). Waves 0-3 <-> node
// A, 4-7 <-> node B; each wave: 4 children, online softmax (r11-identical
// per-node arithmetic). xf staged once per block (halved staging traffic).
__global__ __launch_bounds__(512) void attn_k(const int* __restrict__ trees,
                                              const float* __restrict__ cmask,
                                              const short* __restrict__ tab,
                                              const short* __restrict__ dp_b,
                                              const float* __restrict__ attnv,
                                              const short* __restrict__ xiou_b,
                                              short* __restrict__ hjb,
                                              float* __restrict__ fsum) {
    __shared__ int sidx[32];
    __shared__ float smask[32];
    __shared__ short xfL[16 * 256];   // 8 KB
    __shared__ float hjp[8 * 256];    // 8 KB per-wave partials
    __shared__ float fsp[8 * 256];    // 8 KB
    __shared__ float mw[8], dw[8];
    const int tid = threadIdx.x;
    const int w = tid >> 6, lane = tid & 63;
    const int e0 = lane * 4;
    const int nn = w >> 2;                    // node within block (0/1)
    const int node = blockIdx.x * 2 + nn;
    const int bb = (blockIdx.x * 2) >> 8;     // batch (block-uniform; pairs never straddle)
    const int cbase = nn * 16;
    if (tid < 32) {
        sidx[tid] = trees[blockIdx.x * 32 + tid];
        smask[tid] = cmask[blockIdx.x * 32 + tid];
    }
    {   // stage x_f rows j=0..15 of batch bb (bf16): 512 int4s, one per thread
        const int j = tid >> 5, cc = (tid & 31) * 8;
        *(int4*)(xfL + j * 256 + cc) =
            *(const int4*)(xiou_b + (size_t)(bb * 256 + j) * 1024 + 768 + cc);
    }
    __syncthreads();

    const float4 av = *(const float4*)(attnv + e0);
    float m_run = -1e30f, d_run = 0.0f;
    float hj0 = 0.f, hj1 = 0.f, hj2 = 0.f, hj3 = 0.f;
    float fs0 = 0.f, fs1 = 0.f, fs2 = 0.f, fs3 = 0.f;
#pragma unroll
    for (int jj = 0; jj < 4; jj++) {
        const int j = (w & 3) * 4 + jj;
        if (smask[cbase + j] == 0.0f) continue;  // exact: masked terms are x 0 in ref
        const int idx = sidx[cbase + j];
        const short* row = tab + (size_t)idx * 1024;
        short4 ph = *(const short4*)(row + e0);
        short4 dv = *(const short4*)(dp_b + ((size_t)node * 16 + j) * 256 + e0);
        float s = tanh_(b2f(ph.x) + b2f(dv.x)) * av.x
                + tanh_(b2f(ph.y) + b2f(dv.y)) * av.y
                + tanh_(b2f(ph.z) + b2f(dv.z)) * av.z
                + tanh_(b2f(ph.w) + b2f(dv.w)) * av.w;
#pragma unroll
        for (int off = 32; off > 0; off >>= 1) s += __shfl_xor(s, off);
        float wt;
        if (s > m_run) {  // wave-uniform branch
            const float sc = __expf(m_run - s);
            d_run = fmaf(d_run, sc, 1.0f);
            hj0 *= sc; hj1 *= sc; hj2 *= sc; hj3 *= sc;
            m_run = s; wt = 1.0f;
        } else {
            wt = __expf(s - m_run);
            d_run += wt;
        }
        short4 rh = *(const short4*)(row + 512 + e0);
        short4 cb = *(const short4*)(row + 768 + e0);
        short4 pf = *(const short4*)(row + 256 + e0);
        short4 xf = *(const short4*)(xfL + j * 256 + e0);
        hj0 = fmaf(b2f(rh.x), wt, hj0);
        hj1 = fmaf(b2f(rh.y), wt, hj1);
        hj2 = fmaf(b2f(rh.z), wt, hj2);
        hj3 = fmaf(b2f(rh.w), wt, hj3);
        fs0 = fmaf(sigmoid_(b2f(xf.x) + b2f(pf.x)), b2f(cb.x), fs0);
        fs1 = fmaf(sigmoid_(b2f(xf.y) + b2f(pf.y)), b2f(cb.y), fs1);
        fs2 = fmaf(sigmoid_(b2f(xf.z) + b2f(pf.z)), b2f(cb.z), fs2);
        fs3 = fmaf(sigmoid_(b2f(xf.w) + b2f(pf.w)), b2f(cb.w), fs3);
    }
    *(float4*)(hjp + w * 256 + e0) = make_float4(hj0, hj1, hj2, hj3);
    *(float4*)(fsp + w * 256 + e0) = make_float4(fs0, fs1, fs2, fs3);
    if (lane == 0) { mw[w] = m_run; dw[w] = d_run; }
    __syncthreads();
    // cross-wave combine per node: tid = nc*256 + element
    const int nc = tid >> 8, e = tid & 255;
    const int w0 = nc * 4;
    const float m = fmaxf(fmaxf(mw[w0], mw[w0 + 1]), fmaxf(mw[w0 + 2], mw[w0 + 3]));
    float D = 0.f, hv = 0.f, fv = 0.f;
#pragma unroll
    for (int ww = 0; ww < 4; ww++) {
        const float sc = __expf(mw[w0 + ww] - m);
        D = fmaf(dw[w0 + ww], sc, D);
        hv = fmaf(hjp[(w0 + ww) * 256 + e], sc, hv);
        fv += fsp[(w0 + ww) * 256 + e];
    }
    const float inv = (D > 0.0f) ? 1.0f / D : 0.0f;  // all-masked: hj = 0
    const int gnode = blockIdx.x * 2 + nc;
    hjb[(size_t)gnode * 256 + e] = f2b(hv * inv);
    fsum[(size_t)gnode * 256 + e] = fv;
}

// Post stage: 16 nodes/block, 256 blocks, 512 threads. h_iou MFMA -> gates
// (bf16 x_iou) -> renorm -> proj MFMA; writes packed tab rows.
// first=1 (level 0): h=c=0 exactly => h_iou=0, fsum=0 — skip phases 1-2.
__global__ __launch_bounds__(512, 2) void post_k(const short* __restrict__ hjb,
                                                 const float* __restrict__ fsum,
                                                 const short* __restrict__ xiou_b,
                                                 const short* __restrict__ WThiou,
                                                 const float* __restrict__ b_hiou,
                                                 const short* __restrict__ WTcat,
                                                 const float* __restrict__ biascat,
                                                 short* __restrict__ tab,
                                                 float* __restrict__ out,
                                                 int first, int last) {
    __shared__ short hjA[16 * 264];
    __shared__ short htA[16 * 264];
    __shared__ float hiouL[16 * 768];   // 48 KB
    const int tid = threadIdx.x;
    const int w = tid >> 6, lane = tid & 63;
    const int r16 = lane & 15, q = lane >> 4;
    const int node0 = blockIdx.x * 16;
    const int b = node0 >> 8, t0 = node0 & 255;

    if (!first) {
        // Phase 1: stage hj tile (16 rows x 256 bf16); 512 int4s, one each
        {
            const int row = tid >> 5, c0 = (tid & 31) * 8;
            *(int4*)(hjA + row * 264 + c0) =
                *(const int4*)(hjb + (size_t)(node0 + row) * 256 + c0);
        }
        __syncthreads();
        // Phase 2: h_iou = hj(16x256) @ W_hiou -> hiouL; 48 N-frags / 8 waves
        for (int f = 0; f < 6; f++) {
            const int nf = w * 6 + f;
            f32x4 acc = {};
#pragma unroll
            for (int kt = 0; kt < 8; kt++) {
                bf16x8 af = *(const bf16x8*)(hjA + r16 * 264 + kt * 32 + q * 8);
                bf16x8 bf = *(const bf16x8*)(WThiou + (size_t)(nf * 16 + r16) * 256 + kt * 32 + q * 8);
                acc = __builtin_amdgcn_mfma_f32_16x16x32_bf16(af, bf, acc, 0, 0, 0);
            }
#pragma unroll
            for (int r = 0; r < 4; r++)
                hiouL[(q * 4 + r) * 768 + nf * 16 + r16] = acc[r];
        }
        __syncthreads();
    }

    // Phase 3: gates + renorm. Thread t: node nl = t>>5, elems e0g..e0g+7.
    {
        const int nl = tid >> 5, e0g = (tid & 31) * 8;
        const int gnode = node0 + nl;
        const short* xr = xiou_b + (size_t)gnode * 1024;
        const float* hl = hiouL + nl * 768;
        float hn[8], cn[8], hs = 0.0f, cs = 0.0f;
#pragma unroll
        for (int u = 0; u < 8; u += 4) {
            short4 xi = *(const short4*)(xr + e0g + u);
            short4 xo = *(const short4*)(xr + 256 + e0g + u);
            short4 xu = *(const short4*)(xr + 512 + e0g + u);
            float4 hi, ho, hu, fv;
            if (!first) {
                hi = *(const float4*)(hl + e0g + u);
                ho = *(const float4*)(hl + 256 + e0g + u);
                hu = *(const float4*)(hl + 512 + e0g + u);
                fv = *(const float4*)(fsum + (size_t)gnode * 256 + e0g + u);
            } else {  // level 0: h_j = 0 => h_iou = 0; fsum = 0 (exact)
                hi = make_float4(0.f, 0.f, 0.f, 0.f);
                ho = hi; hu = hi; fv = hi;
            }
            float4 bi = *(const float4*)(b_hiou + e0g + u);
            float4 bo = *(const float4*)(b_hiou + 256 + e0g + u);
            float4 bu = *(const float4*)(b_hiou + 512 + e0g + u);
            float iv[4] = { b2f(xi.x) + hi.x + bi.x, b2f(xi.y) + hi.y + bi.y,
                            b2f(xi.z) + hi.z + bi.z, b2f(xi.w) + hi.w + bi.w };
            float ov[4] = { b2f(xo.x) + ho.x + bo.x, b2f(xo.y) + ho.y + bo.y,
                            b2f(xo.z) + ho.z + bo.z, b2f(xo.w) + ho.w + bo.w };
            float uv[4] = { b2f(xu.x) + hu.x + bu.x, b2f(xu.y) + hu.y + bu.y,
                            b2f(xu.z) + hu.z + bu.z, b2f(xu.w) + hu.w + bu.w };
            float fa[4] = { fv.x, fv.y, fv.z, fv.w };
#pragma unroll
            for (int z = 0; z < 4; z++) {
                const float c = fmaf(sigmoid_(iv[z]), tanh_(uv[z]), fa[z]);
                const float h = sigmoid_(ov[z]) * tanh_(c);
                cn[u + z] = c; hn[u + z] = h;
                hs = fmaf(h, h, hs); cs = fmaf(c, c, cs);
            }
        }
        if (last) {
#pragma unroll
            for (int u = 0; u < 8; u += 4)
                *(float4*)(out + (size_t)gnode * 256 + e0g + u) =
                    make_float4(hn[u], hn[u + 1], hn[u + 2], hn[u + 3]);
            return;  // uniform across grid
        }
        // row-norm across the node's 32 threads
#pragma unroll
        for (int off = 16; off > 0; off >>= 1) {
            hs += __shfl_xor(hs, off);
            cs += __shfl_xor(cs, off);
        }
        const float nh = sqrtf(hs), ncv = sqrtf(cs);
        const float sh = nh > 2.0f ? 2.0f / nh : 1.0f;
        const float sc = ncv > 2.0f ? 2.0f / ncv : 1.0f;
        const size_t grow = (size_t)b * (Tz + 2) + t0 + nl + 2;
        short hb[8], cb[8];
#pragma unroll
        for (int u = 0; u < 8; u++) {
            hb[u] = f2b(hn[u] * sh);
            cb[u] = f2b(cn[u] * sc);
        }
#pragma unroll
        for (int u = 0; u < 8; u += 4) {
            *(short4*)(tab + grow * 1024 + 512 + e0g + u) = *(short4*)&hb[u];
            *(short4*)(tab + grow * 1024 + 768 + e0g + u) = *(short4*)&cb[u];
            *(short4*)(htA + nl * 264 + e0g + u) = *(short4*)&hb[u];
        }
    }
    __syncthreads();

    // Phase 4: [ph|pf] = rn_h(16x256) @ [W_hproj|W_hf] + [0|b_hf] -> tab 0..511
    for (int f = 0; f < 4; f++) {
        const int nf = w * 4 + f;
        f32x4 acc = {};
#pragma unroll
        for (int kt = 0; kt < 8; kt++) {
            bf16x8 af = *(const bf16x8*)(htA + r16 * 264 + kt * 32 + q * 8);
            bf16x8 bf = *(const bf16x8*)(WTcat + (size_t)(nf * 16 + r16) * 256 + kt * 32 + q * 8);
            acc = __builtin_amdgcn_mfma_f32_16x16x32_bf16(af, bf, acc, 0, 0, 0);
        }
        const int col = nf * 16 + r16;
        const float bc = biascat[col];
#pragma unroll
        for (int r = 0; r < 4; r++) {
            const size_t grow = (size_t)b * (Tz + 2) + t0 + q * 4 + r + 2;
            tab[grow * 1024 + col] = f2b(acc[r] + bc);
        }
    }
}

extern "C" void kernel_launch(void* const* d_in, const int* in_sizes, int n_in,
                              void* d_out, int out_size, void* d_ws, size_t ws_size,
                              hipStream_t stream) {
    const float* tok     = (const float*)d_in[0];
    const int*   trees   = (const int*)d_in[1];
    const float* cmask   = (const float*)d_in[2];
    const float* cdep    = (const float*)d_in[4];
    const float* W_xiouf = (const float*)d_in[5];
    const float* b_xiouf = (const float*)d_in[6];
    const float* W_hiou  = (const float*)d_in[7];
    const float* b_hiou  = (const float*)d_in[8];
    const float* W_hf    = (const float*)d_in[9];
    const float* b_hf    = (const float*)d_in[10];
    const float* W_dep   = (const float*)d_in[11];
    const float* W_hp    = (const float*)d_in[12];
    const float* W_attnv = (const float*)d_in[13];
    float* out = (float*)d_out;

    char* p = (char*)d_ws;
    auto alloc = [&](size_t bytes) { char* q = p; p += (bytes + 255) & ~255ull; return q; };
    short* tab    = (short*)alloc((size_t)ROWSz * 1024 * 2);       // 8.5 MB packed
    short* dp_b   = (short*)alloc((size_t)NODESz * 16 * 256 * 2);  // 33.5 MB
    short* xiou_b = (short*)alloc((size_t)NODESz * 1024 * 2);      // 8.4 MB bf16
    short* hjb    = (short*)alloc((size_t)NODESz * 256 * 2);
    float* fsumb  = (float*)alloc((size_t)NODESz * 256 * 4);
    short* tok_b  = (short*)alloc((size_t)NODESz * 256 * 2);
    short* cdep_b = (short*)alloc((size_t)NODESz * 16 * 64 * 2);
    short* WTx    = (short*)alloc(262144 * 2);
    short* WTcat  = (short*)alloc(131072 * 2);
    short* WThiou = (short*)alloc(196608 * 2);
    short* WTdep  = (short*)alloc(16384 * 2);
    float* biascat= (float*)alloc(512 * 4);

    prep_all_k<<<PREP_BLOCKS, 256, 0, stream>>>(W_xiouf, W_hp, W_hf, b_hf, W_hiou,
                                                W_dep, tok, cdep,
                                                WTx, WTcat, WThiou, WTdep, biascat,
                                                tok_b, cdep_b, tab);

    // Loop-invariant GEMMs: x_iou (bf16 out incl. bias) and deprel projection
    bgemm_k<<<dim3(16, 64), 256, 0, stream>>>(tok_b, WTx, b_xiouf, nullptr, xiou_b, 256, 1024);
    bgemm_k<<<dim3(4, 1024), 256, 0, stream>>>(cdep_b, WTdep, nullptr, nullptr, dp_b, 64, 256);

    // Level 0: h=c=0 => no gathers; elementwise gates + proj only.
    post_k<<<NODESz / 16, 512, 0, stream>>>(nullptr, nullptr, xiou_b,
                                            WThiou, b_hiou, WTcat, biascat,
                                            tab, out, 1, 0);
    // Levels 1..7
    for (int lvl = 1; lvl < DEPTHz; lvl++) {
        attn_k<<<NODESz / 2, 512, 0, stream>>>(trees, cmask, tab, dp_b, W_attnv,
                                               xiou_b, hjb, fsumb);
        post_k<<<NODESz / 16, 512, 0, stream>>>(hjb, fsumb, xiou_b,
                                                WThiou, b_hiou, WTcat, biascat,
                                                tab, out, 0, lvl == DEPTHz - 1);
    }
}